// Round 1
// baseline (424.264 us; speedup 1.0000x reference)
//
#include <hip/hip_runtime.h>
#include <math.h>

// Problem constants (fixed by the reference)
#define NB 32       // batch
#define ND 1024     // CTX_DIM
#define NC 2048     // CTX_SIZE
#define NH 1024     // HID
#define NSEQ 64     // seqlen
#define CCHUNK 32   // c-tile width per block
#define NCHUNK (NC / CCHUNK)   // 64 chunks per batch

// ---------------------------------------------------------------------------
// k1: v[b,d] = sum_h hidden[b,h] * W[h,d]
// grid = 32 b * 8 dchunks(128) = 256 blocks, 128 threads
// W rows read coalesced; hidden[b,h] is wave-uniform (scalar load).
// ---------------------------------------------------------------------------
__global__ __launch_bounds__(128) void k1_v(const float* __restrict__ hidden,
                                            const float* __restrict__ W,
                                            float* __restrict__ v) {
  const int b = blockIdx.x >> 3;
  const int d = ((blockIdx.x & 7) << 7) + threadIdx.x;
  const float* hb = hidden + b * NH;
  float acc = 0.f;
#pragma unroll 16
  for (int h = 0; h < NH; ++h) acc += hb[h] * W[h * ND + d];
  v[b * ND + d] = acc;
}

// ---------------------------------------------------------------------------
// k2: fused scores + chunk-local softmax + weighted partial sums.
// One block per (b, c-chunk of 32). Tile [d][c] = 1024x32 fp32 = 128 KB LDS.
// Scores are computed DURING the global->LDS staging (hidden under HBM).
// Outputs: accp[bid][d] = sum_c exp(s_c - m)*ctx[b,d,c]   (rows = d_out!)
//          ml[bid] = {m, l}
// ---------------------------------------------------------------------------
__global__ __launch_bounds__(256) void k2_main(const float* __restrict__ ctx,
                                               const float* __restrict__ v,
                                               float* __restrict__ accp,
                                               float* __restrict__ ml) {
  __shared__ __align__(16) float tile[ND * CCHUNK];  // 128 KB, [d][c]
  __shared__ __align__(16) float vs[ND];             // 4 KB
  __shared__ __align__(16) float4 sred[256];         // 4 KB score partials
  __shared__ __align__(16) float pf[CCHUNK];         // softmax weights

  const int t = threadIdx.x;
  const int bid = blockIdx.x;
  const int b = bid >> 6;            // / NCHUNK
  const int c0 = (bid & 63) * CCHUNK;

  // stage v[b,:] into LDS (4 KB)
  {
    float4 vv = *(const float4*)(v + b * ND + t * 4);
    *(float4*)(vs + t * 4) = vv;
  }
  __syncthreads();

  // --- Phase A+B merged: stream tile in, FMA scores on the fly ---
  // thread t: c-group cg = t&7 (4 c's), d-part dp = t>>3; d = dp + 32*j
  const int cg = t & 7;
  const int dp = t >> 3;
  const float* gp = ctx + (size_t)b * ND * NC + (size_t)dp * NC + c0 + cg * 4;
  float* tw = tile + dp * CCHUNK + cg * 4;
  float4 s4 = make_float4(0.f, 0.f, 0.f, 0.f);
#pragma unroll 8
  for (int j = 0; j < 32; ++j) {
    float4 x = *(const float4*)(gp + (size_t)32 * NC * j);
    *(float4*)(tw + 32 * CCHUNK * j) = x;   // bank group cg*4 -> conflict-free
    float vd = vs[dp + 32 * j];             // broadcast read
    s4.x += x.x * vd; s4.y += x.y * vd; s4.z += x.z * vd; s4.w += x.w * vd;
  }
  sred[t] = s4;   // flat word index t*4+comp == dp*32 + c
  __syncthreads();

  // --- chunk-local softmax (lanes 0..31 of wave 0) ---
  if (t < 32) {
    const float* sr = (const float*)sred;
    float s = 0.f;
#pragma unroll
    for (int p = 0; p < 32; ++p) s += sr[p * 32 + t];   // bank t, conflict-free
    float mm = s;
#pragma unroll
    for (int off = 16; off; off >>= 1) mm = fmaxf(mm, __shfl_xor(mm, off, 32));
    float e = __expf(s - mm);
    float ls = e;
#pragma unroll
    for (int off = 16; off; off >>= 1) ls += __shfl_xor(ls, off, 32);
    pf[t] = e;
    if (t == 0) { ml[bid * 2] = mm; ml[bid * 2 + 1] = ls; }
  }
  __syncthreads();

  // --- Phase C: acc[d] = sum_c p[c] * tile[d][c], rotated reads ---
  float4 pr[8];
#pragma unroll
  for (int j = 0; j < 8; ++j)
    pr[j] = *(const float4*)(pf + ((j + t) & 7) * 4);  // static reg slots

  float* ao = accp + (size_t)bid * ND;
#pragma unroll
  for (int k = 0; k < 4; ++k) {
    const int d = t + 256 * k;
    const float* tr = tile + d * CCHUNK;
    float a = 0.f;
#pragma unroll
    for (int j = 0; j < 8; ++j) {
      const int jr = (j + t) & 7;                      // bank rotation
      float4 x = *(const float4*)(tr + jr * 4);
      float4 pp = pr[j];
      a += x.x * pp.x + x.y * pp.y + x.z * pp.z + x.w * pp.w;
    }
    ao[d] = a;
  }
}

// ---------------------------------------------------------------------------
// k3: online-softmax combine across the 64 chunks of each b.
// grid = 32 b * 4 d-quarters = 128 blocks, 256 threads.
// ctx[b,d] = (sum_i e^{m_i-m_g} acc_i[d]) / (sum_i e^{m_i-m_g} l_i)
// ---------------------------------------------------------------------------
__global__ __launch_bounds__(256) void k3_combine(const float* __restrict__ accp,
                                                  const float* __restrict__ ml,
                                                  float* __restrict__ ctxo) {
  __shared__ float sc[64];
  __shared__ float sinv;
  const int b = blockIdx.x >> 2;
  const int dq = blockIdx.x & 3;
  const int t = threadIdx.x;
  if (t < 64) {
    float mi = ml[(b * 64 + t) * 2];
    float li = ml[(b * 64 + t) * 2 + 1];
    float mg = mi;
#pragma unroll
    for (int off = 32; off; off >>= 1) mg = fmaxf(mg, __shfl_xor(mg, off, 64));
    float scale = __expf(mi - mg);
    float dpart = scale * li;
#pragma unroll
    for (int off = 32; off; off >>= 1) dpart += __shfl_xor(dpart, off, 64);
    sc[t] = scale;
    if (t == 0) sinv = 1.0f / dpart;
  }
  __syncthreads();
  const int d = dq * 256 + t;
  const float* ap = accp + (size_t)b * 64 * ND + d;
  float acc = 0.f;
#pragma unroll 8
  for (int i = 0; i < 64; ++i) acc += sc[i] * ap[i * ND];
  ctxo[b * ND + d] = acc * sinv;
}

// ---------------------------------------------------------------------------
// k4: broadcast ctx[b,d] to out[s,b,d] for s=0..63. Overwrites d_out fully.
// ---------------------------------------------------------------------------
__global__ __launch_bounds__(256) void k4_bcast(const float* __restrict__ ctxo,
                                               float* __restrict__ out) {
  const int sb = blockIdx.x;          // s*32 + b
  const int b = sb & 31;
  const int t = threadIdx.x;
  float4 x = *(const float4*)(ctxo + b * ND + t * 4);
  *(float4*)(out + (size_t)sb * ND + t * 4) = x;
}

extern "C" void kernel_launch(void* const* d_in, const int* in_sizes, int n_in,
                              void* d_out, int out_size, void* d_ws, size_t ws_size,
                              hipStream_t stream) {
  (void)in_sizes; (void)n_in; (void)out_size; (void)ws_size;
  // d_in: [0]=seqlen(int,1) [1]=hidden(1,32,1024) [2]=contextvects(32,1024,2048)
  //       [3]=W(1024,1024) [4]=b(1024)  -- bias is softmax-invariant, unused.
  const float* hidden = (const float*)d_in[1];
  const float* ctxv   = (const float*)d_in[2];
  const float* W      = (const float*)d_in[3];
  float* out = (float*)d_out;

  char* ws = (char*)d_ws;
  float* v    = (float*)(ws);              // 32*1024 fp32 = 128 KB
  float* ml   = (float*)(ws + 131072);     // 2048*2 fp32 = 16 KB
  float* ctxo = (float*)(ws + 147456);     // 32*1024 fp32 = 128 KB

  // Partial accumulators (2048 x 1024 fp32 = 8 MB) live in d_out exactly;
  // k3 consumes them into ws, k4 overwrites d_out with the final broadcast.
  k1_v<<<256, 128, 0, stream>>>(hidden, W, v);
  k2_main<<<NB * NCHUNK, 256, 0, stream>>>(ctxv, v, out, ml);
  k3_combine<<<128, 256, 0, stream>>>(out, ml, ctxo);
  k4_bcast<<<NSEQ * NB, 256, 0, stream>>>(ctxo, out);
}